// Round 2
// baseline (224.794 us; speedup 1.0000x reference)
//
#include <hip/hip_runtime.h>
#include <stdint.h>

#define N_NODES 100000
#define N_FEAT 128
#define N_EDGES 3200000
#define GEMM_BLOCKS 1563          // ceil(100000 / 64)
#define SCAT_BLOCKS 12500         // N_EDGES / 256

// ---------- bf16 helpers ----------
static __device__ __forceinline__ unsigned int f2bf_u(float f) {
    unsigned int u = __float_as_uint(f);
    u += 0x7FFFu + ((u >> 16) & 1u);   // RNE
    return u >> 16;
}

typedef __bf16 bf16x8 __attribute__((ext_vector_type(8)));
typedef float f32x4 __attribute__((ext_vector_type(4)));

// ---------- Kernel 1: XF = x @ F (MFMA) + biased-u8 quant; extra blocks do CSR scatter ----------
// blocks [0,GEMM_BLOCKS): 4 waves, 64 rows/block. F converted fp32->bf16 into LDS
//   fragment-linear by the block itself (64KB table, L2-resident).
//   flat short index i: s=i&7, lane=(i>>3)&63, kkidx=(i>>9)&3, j=i>>11
//   holds F[k][n], n = (i>>11)*16 + ((i>>3)&15), k = ((i>>9)&3)*32 + ((i>>7)&3)*8 + (i&7)
// blocks [GEMM_BLOCKS, GEMM_BLOCKS+SCAT_BLOCKS): CSR row_ptr scatter from sorted edge_dst.
// Packed xi8 layout: byte b of uint c of a row = feature (32*b + c).
__global__ __launch_bounds__(256) void k_xf(
        const float* __restrict__ x, const float* __restrict__ f,
        const int* __restrict__ dst, int* __restrict__ row_ptr,
        unsigned int* __restrict__ xi8,          // [N][32] uints (4 biased-u8 each)
        float* __restrict__ xscale) {            // [N]
    int b = blockIdx.x;
    int t = threadIdx.x;
    if (b >= GEMM_BLOCKS) {                      // ---- CSR scatter role ----
        int e = (b - GEMM_BLOCKS) * 256 + t;
        if (e >= N_EDGES) return;
        int dcur = dst[e];
        if (e == 0) {
            for (int d = 0; d <= dcur; ++d) row_ptr[d] = 0;
        } else {
            int dprev = dst[e - 1];
            for (int d = dprev + 1; d <= dcur; ++d) row_ptr[d] = e;
        }
        if (e == N_EDGES - 1) {
            for (int d = dcur + 1; d <= N_NODES; ++d) row_ptr[d] = N_EDGES;
        }
        return;
    }

    __shared__ unsigned short Bbuf[16384];       // 32768 B exactly (5 blocks/CU)
#pragma unroll 8
    for (int i = 0; i < 64; ++i) {
        int idx = t + i * 256;                   // flat fragment-linear index
        int n = ((idx >> 11) << 4) | ((idx >> 3) & 15);
        int k = (((idx >> 9) & 3) << 5) | (((idx >> 7) & 3) << 3) | (idx & 7);
        Bbuf[idx] = (unsigned short)f2bf_u(f[k * 128 + n]);
    }
    __syncthreads();

    int wave = t >> 6, lane = t & 63, m15 = lane & 15, q = lane >> 4;
    int row = blockIdx.x * 64 + wave * 16 + m15;
    int rowc = min(row, N_NODES - 1);            // clamp loads; stores guarded

    f32x4 acc[8];
#pragma unroll
    for (int j = 0; j < 8; ++j) acc[j] = f32x4{0.f, 0.f, 0.f, 0.f};

#pragma unroll
    for (int kkidx = 0; kkidx < 4; ++kkidx) {
        const float* ap = x + (size_t)rowc * 128 + kkidx * 32 + q * 8;
        float4 v0 = *(const float4*)ap;
        float4 v1 = *(const float4*)(ap + 4);
        union { bf16x8 v; unsigned short s[8]; } au;
        au.s[0] = (unsigned short)f2bf_u(v0.x);
        au.s[1] = (unsigned short)f2bf_u(v0.y);
        au.s[2] = (unsigned short)f2bf_u(v0.z);
        au.s[3] = (unsigned short)f2bf_u(v0.w);
        au.s[4] = (unsigned short)f2bf_u(v1.x);
        au.s[5] = (unsigned short)f2bf_u(v1.y);
        au.s[6] = (unsigned short)f2bf_u(v1.z);
        au.s[7] = (unsigned short)f2bf_u(v1.w);
#pragma unroll
        for (int j = 0; j < 8; ++j) {
            bf16x8 bfrag = *(const bf16x8*)(Bbuf + (((j * 4 + kkidx) * 64 + lane) * 8));
            acc[j] = __builtin_amdgcn_mfma_f32_16x16x32_bf16(au.v, bfrag, acc[j], 0, 0, 0);
        }
    }

    int rowbase = blockIdx.x * 64 + wave * 16 + q * 4;   // D: row=q*4+r, col=j*16+m15
#pragma unroll
    for (int r = 0; r < 4; ++r) {
        float mx = 0.f;
#pragma unroll
        for (int j = 0; j < 8; ++j) mx = fmaxf(mx, fabsf(acc[j][r]));
        for (int d = 1; d < 16; d <<= 1) mx = fmaxf(mx, __shfl_xor(mx, d));
        float inv = 127.f / fmaxf(mx, 1e-20f);
        unsigned int u0 = 0, u1 = 0;
#pragma unroll
        for (int bb = 0; bb < 4; ++bb) {
            unsigned int q0 = (unsigned int)(int)(rintf(acc[2 * bb][r] * inv) + 128.f);
            unsigned int q1 = (unsigned int)(int)(rintf(acc[2 * bb + 1][r] * inv) + 128.f);
            u0 |= (q0 & 0xFFu) << (8 * bb);
            u1 |= (q1 & 0xFFu) << (8 * bb);
        }
        int gr = rowbase + r;
        if (gr < N_NODES) {
            xi8[(size_t)gr * 32 + m15] = u0;       // uint c=m15       (feats 32b+c)
            xi8[(size_t)gr * 32 + 16 + m15] = u1;  // uint c=16+m15
            if (m15 == 0) xscale[gr] = mx * (1.f / 127.f);
        }
    }
}

// ---------- Kernel 2: out[d] = sum_e w_e * xscale[s] * (q_u - 128) -> fp32 direct ----------
// 4 lane-groups of 16; group g takes edge (j*16 + u*4 + g); lane covers 8 feats
// via one uint2 (8B) gather. 2-deep register double-buffer across 16-edge groups.
// -128 bias corrected once per node through aw (sum of folded weights) -- exact.
__global__ __launch_bounds__(256) void k_aggregate(
        const unsigned int* __restrict__ xi8,    // [N][32] uints (4 biased-u8 each)
        const float* __restrict__ xscale,        // [N]
        const int* __restrict__ src,
        const float* __restrict__ w,
        const int* __restrict__ row_ptr,
        float* __restrict__ out) {               // [N][128] fp32 (final output)
    __shared__ uint2 smeta[4][64];
    int wave = threadIdx.x >> 6, lane = threadIdx.x & 63;
    int node = blockIdx.x * 4 + wave;
    if (node >= N_NODES) return;
    int g = lane >> 4, f16 = lane & 15;
    unsigned int f16o = (unsigned int)(f16 * 8);     // byte offset within row
    int start = row_ptr[node], end = row_ptr[node + 1];
    uint2* sm = smeta[wave];
    const char* xb = (const char*)xi8;               // uniform base -> saddr form

    float a[8] = {0.f, 0.f, 0.f, 0.f, 0.f, 0.f, 0.f, 0.f};
    float aw = 0.f;

#define LOADJ(J, VV, WW) do {                                              \
        _Pragma("unroll")                                                  \
        for (int u = 0; u < 4; ++u) {                                      \
            uint2 mm = sm[(J) * 16 + u * 4 + g];                           \
            WW[u] = __uint_as_float(mm.y);                                 \
            VV[u] = *(const uint2*)(xb + (mm.x + f16o));                   \
        } } while (0)
#define FMAJ(VV, WW) do {                                                  \
        _Pragma("unroll")                                                  \
        for (int u = 0; u < 4; ++u) {                                      \
            unsigned int lo = VV[u].x, hi = VV[u].y; float wu = WW[u];     \
            aw += wu;                                                      \
            a[0] = fmaf(wu, (float)( lo        & 0xFFu), a[0]);            \
            a[1] = fmaf(wu, (float)((lo >>  8) & 0xFFu), a[1]);            \
            a[2] = fmaf(wu, (float)((lo >> 16) & 0xFFu), a[2]);            \
            a[3] = fmaf(wu, (float)( lo >> 24         ), a[3]);            \
            a[4] = fmaf(wu, (float)( hi        & 0xFFu), a[4]);            \
            a[5] = fmaf(wu, (float)((hi >>  8) & 0xFFu), a[5]);            \
            a[6] = fmaf(wu, (float)((hi >> 16) & 0xFFu), a[6]);            \
            a[7] = fmaf(wu, (float)( hi >> 24         ), a[7]);            \
        } } while (0)

    for (int e0 = start; e0 < end; e0 += 64) {
        int e = e0 + lane;
        uint2 m = make_uint2(0u, 0u);                    // pad: row 0, w'=0
        if (e < end) {
            int sv = src[e];
            m.x = (unsigned int)sv << 7;                 // row byte offset
            m.y = __float_as_uint(w[e] * xscale[sv]);    // fold row scale
        }
        sm[lane] = m;                                    // wave-private; no barrier
        int nj = (min(64, end - e0) + 15) >> 4;          // 16-edge groups
        uint2 v0[4], v1[4]; float w0[4], w1[4];
        LOADJ(0, v0, w0);
        int j = 0;
        for (; j + 2 <= nj; j += 2) {
            LOADJ(j + 1, v1, w1);
            FMAJ(v0, w0);
            if (j + 2 < nj) LOADJ(j + 2, v0, w0);
            FMAJ(v1, w1);
        }
        if (j < nj) FMAJ(v0, w0);
    }

    // cross-group reduction (features depend only on f16)
#pragma unroll
    for (int k = 0; k < 8; ++k) {
        a[k] += __shfl_xor(a[k], 16);
        a[k] += __shfl_xor(a[k], 32);
    }
    aw += __shfl_xor(aw, 16);
    aw += __shfl_xor(aw, 32);
#pragma unroll
    for (int k = 0; k < 8; ++k) a[k] = fmaf(-128.f, aw, a[k]);  // undo +128 bias

    if (g == 0) {
        // a[0..3]: uint c=2*f16   -> feats c, c+32, c+64, c+96
        // a[4..7]: uint c=2*f16+1 -> feats c+1, c+33, c+65, c+97
        float* o = out + (size_t)node * 128 + f16 * 2;
        *(float2*)(o)      = make_float2(a[0], a[4]);
        *(float2*)(o + 32) = make_float2(a[1], a[5]);
        *(float2*)(o + 64) = make_float2(a[2], a[6]);
        *(float2*)(o + 96) = make_float2(a[3], a[7]);
    }
#undef LOADJ
#undef FMAJ
}

extern "C" void kernel_launch(void* const* d_in, const int* in_sizes, int n_in,
                              void* d_out, int out_size, void* d_ws, size_t ws_size,
                              hipStream_t stream) {
    const float* x        = (const float*)d_in[0];
    const float* filters  = (const float*)d_in[1];
    const int*   edge_src = (const int*)d_in[2];
    const int*   edge_dst = (const int*)d_in[3];
    const float* edge_w   = (const float*)d_in[4];
    float* out = (float*)d_out;

    char* ws = (char*)d_ws;
    unsigned int* xi8 = (unsigned int*)(ws);                          // 12.8 MB
    float*        xsc = (float*)       (ws + 13ll * 1024 * 1024);     // 400 KB
    int*          rp  = (int*)         (ws + 15ll * 1024 * 1024);     // 400 KB

    hipLaunchKernelGGL(k_xf, dim3(GEMM_BLOCKS + SCAT_BLOCKS), dim3(256), 0, stream,
                       x, filters, edge_dst, rp, xi8, xsc);
    hipLaunchKernelGGL(k_aggregate, dim3(25000), dim3(256), 0, stream,
                       xi8, xsc, edge_src, edge_w, rp, out);
}

// Round 3
// 200.950 us; speedup vs baseline: 1.1187x; 1.1187x over previous
//
#include <hip/hip_runtime.h>
#include <stdint.h>

#define N_NODES 100000
#define N_FEAT 128
#define N_EDGES 3200000

// ---------- bf16 helpers ----------
static __device__ __forceinline__ unsigned int f2bf_u(float f) {
    unsigned int u = __float_as_uint(f);
    u += 0x7FFFu + ((u >> 16) & 1u);   // RNE
    return u >> 16;
}

typedef __bf16 bf16x8 __attribute__((ext_vector_type(8)));
typedef float f32x4 __attribute__((ext_vector_type(4)));

// ---------- Kernel 1 (prep): CSR row_ptr + filters -> bf16 fragment-linear ----------
// blocks [0,12500):      CSR row_ptr scatter from sorted edge_dst
// blocks [12500,12564):  filters -> bf16 in MFMA B-fragment-linear order:
//   flat short index i holds F[k][n] with n = (i>>11)*16 + ((i>>3)&15),
//   k = ((i>>9)&3)*32 + ((i>>7)&3)*8 + (i&7)
__global__ __launch_bounds__(256) void k_prep(
        const float* __restrict__ f, unsigned short* __restrict__ fB,
        const int* __restrict__ dst, int* __restrict__ row_ptr) {
    int b = blockIdx.x;
    if (b < 12500) {
        int e = b * 256 + threadIdx.x;
        if (e >= N_EDGES) return;
        int dcur = dst[e];
        if (e == 0) {
            for (int d = 0; d <= dcur; ++d) row_ptr[d] = 0;
        } else {
            int dprev = dst[e - 1];
            for (int d = dprev + 1; d <= dcur; ++d) row_ptr[d] = e;
        }
        if (e == N_EDGES - 1) {
            for (int d = dcur + 1; d <= N_NODES; ++d) row_ptr[d] = N_EDGES;
        }
    } else {
        int i = (b - 12500) * 256 + threadIdx.x;   // flat fragment-linear index
        if (i >= N_FEAT * N_FEAT) return;
        int n = ((i >> 11) << 4) | ((i >> 3) & 15);
        int k = (((i >> 9) & 3) << 5) | (((i >> 7) & 3) << 3) | (i & 7);
        fB[i] = (unsigned short)f2bf_u(f[k * 128 + n]);
    }
}

// ---------- Kernel 2: XF = x @ F (MFMA), fused biased-uint8 row quantization ----------
// Block 256 (4 waves), 64 rows/block. B in LDS fragment-linear (32KB, 5 blocks/CU).
// Packed xi8 layout: byte b of uint c of a row = feature (32*b + c).
__global__ __launch_bounds__(256) void k_xf(
        const float* __restrict__ x,
        const unsigned short* __restrict__ fB,
        unsigned int* __restrict__ xi8,          // [N][32] uints (4 biased-u8 each)
        float* __restrict__ xscale) {            // [N]
    __shared__ unsigned short Bbuf[16384];       // 32768 B exactly
    int t = threadIdx.x;
    for (int i = 0; i < 8; ++i)
        ((uint4*)Bbuf)[t + i * 256] = ((const uint4*)fB)[t + i * 256];
    __syncthreads();

    int wave = t >> 6, lane = t & 63, m15 = lane & 15, q = lane >> 4;
    int row = blockIdx.x * 64 + wave * 16 + m15;
    int rowc = min(row, N_NODES - 1);            // clamp loads; stores guarded

    f32x4 acc[8];
#pragma unroll
    for (int j = 0; j < 8; ++j) acc[j] = f32x4{0.f, 0.f, 0.f, 0.f};

#pragma unroll
    for (int kkidx = 0; kkidx < 4; ++kkidx) {
        const float* ap = x + (size_t)rowc * 128 + kkidx * 32 + q * 8;
        float4 v0 = *(const float4*)ap;
        float4 v1 = *(const float4*)(ap + 4);
        union { bf16x8 v; unsigned short s[8]; } au;
        au.s[0] = (unsigned short)f2bf_u(v0.x);
        au.s[1] = (unsigned short)f2bf_u(v0.y);
        au.s[2] = (unsigned short)f2bf_u(v0.z);
        au.s[3] = (unsigned short)f2bf_u(v0.w);
        au.s[4] = (unsigned short)f2bf_u(v1.x);
        au.s[5] = (unsigned short)f2bf_u(v1.y);
        au.s[6] = (unsigned short)f2bf_u(v1.z);
        au.s[7] = (unsigned short)f2bf_u(v1.w);
#pragma unroll
        for (int j = 0; j < 8; ++j) {
            bf16x8 bfrag = *(const bf16x8*)(Bbuf + (((j * 4 + kkidx) * 64 + lane) * 8));
            acc[j] = __builtin_amdgcn_mfma_f32_16x16x32_bf16(au.v, bfrag, acc[j], 0, 0, 0);
        }
    }

    int rowbase = blockIdx.x * 64 + wave * 16 + q * 4;   // D: row=q*4+r, col=j*16+m15
#pragma unroll
    for (int r = 0; r < 4; ++r) {
        float mx = 0.f;
#pragma unroll
        for (int j = 0; j < 8; ++j) mx = fmaxf(mx, fabsf(acc[j][r]));
        for (int d = 1; d < 16; d <<= 1) mx = fmaxf(mx, __shfl_xor(mx, d));
        float inv = 127.f / fmaxf(mx, 1e-20f);
        unsigned int u0 = 0, u1 = 0;
#pragma unroll
        for (int bb = 0; bb < 4; ++bb) {
            unsigned int q0 = (unsigned int)(int)(rintf(acc[2 * bb][r] * inv) + 128.f);
            unsigned int q1 = (unsigned int)(int)(rintf(acc[2 * bb + 1][r] * inv) + 128.f);
            u0 |= (q0 & 0xFFu) << (8 * bb);
            u1 |= (q1 & 0xFFu) << (8 * bb);
        }
        int gr = rowbase + r;
        if (gr < N_NODES) {
            xi8[(size_t)gr * 32 + m15] = u0;       // uint c=m15      (feats 32b+c)
            xi8[(size_t)gr * 32 + 16 + m15] = u1;  // uint c=16+m15
            if (m15 == 0) xscale[gr] = mx * (1.f / 127.f);
        }
    }
}

// ---------- Kernel 3: out[d] = sum_e w_e * xscale[s] * (q_u - 128) -> fp32 direct ----------
// 8 lane-groups of 8; group g8 handles edge (j*8 + g8) of the staged 64-block;
// lane covers 16 feats via ONE dwordx4 gather (wave: 8 rows = 1KB per instr).
// 2-deep rotate (load j+1 while fma j) keeps >=2KB in flight per wave.
// -128 bias via aw = sum of folded weights, accumulated at staging -- exact.
__global__ __launch_bounds__(256) void k_aggregate(
        const unsigned int* __restrict__ xi8,    // [N][32] uints (4 biased-u8 each)
        const float* __restrict__ xscale,        // [N]
        const int* __restrict__ src,
        const float* __restrict__ w,
        const int* __restrict__ row_ptr,
        float* __restrict__ out) {               // [N][128] fp32 (final output)
    __shared__ uint2 smeta[4][64];
    int wave = threadIdx.x >> 6, lane = threadIdx.x & 63;
    int node = blockIdx.x * 4 + wave;
    if (node >= N_NODES) return;
    int g8 = lane >> 3, l8 = lane & 7;
    unsigned int bo = (unsigned int)(l8 * 16);       // byte offset within 128B row
    int start = row_ptr[node], end = row_ptr[node + 1];
    uint2* sm = smeta[wave];
    const char* xb = (const char*)xi8;

    f32x4 acc[4];                                    // acc[b][cc]: feat 32b+4*l8+cc
#pragma unroll
    for (int b = 0; b < 4; ++b) acc[b] = f32x4{0.f, 0.f, 0.f, 0.f};
    float aw = 0.f;

#define FMAU(QQ, CC) do {                                                    \
        acc[0][CC] = fmaf(wu_, (float)( (QQ)        & 0xFFu), acc[0][CC]);   \
        acc[1][CC] = fmaf(wu_, (float)(((QQ) >>  8) & 0xFFu), acc[1][CC]);   \
        acc[2][CC] = fmaf(wu_, (float)(((QQ) >> 16) & 0xFFu), acc[2][CC]);   \
        acc[3][CC] = fmaf(wu_, (float)( (QQ) >> 24         ), acc[3][CC]);   \
    } while (0)
#define FMAG(V, WUU) do { float wu_ = __uint_as_float(WUU);                  \
        FMAU((V).x, 0); FMAU((V).y, 1); FMAU((V).z, 2); FMAU((V).w, 3);      \
    } while (0)

    for (int e0 = start; e0 < end; e0 += 64) {
        int e = e0 + lane;
        uint2 m = make_uint2(0u, 0u);                // pad: row 0, w'=0
        if (e < end) {
            int sv = src[e];
            m.x = (unsigned int)sv << 7;             // row byte offset
            m.y = __float_as_uint(w[e] * xscale[sv]);// fold row scale
        }
        sm[lane] = m;                                // wave-private; no barrier
        aw += __uint_as_float(m.y);                  // bias sum (staging phase)
        int ng = (min(64, end - e0) + 7) >> 3;       // 8-edge groups (>=1)
        uint2 mm0 = sm[g8];
        uint4 v0 = *(const uint4*)(xb + (mm0.x + bo));
        for (int j = 0; j + 1 < ng; ++j) {
            uint2 mm1 = sm[(j + 1) * 8 + g8];
            uint4 v1 = *(const uint4*)(xb + (mm1.x + bo));
            FMAG(v0, mm0.y);
            mm0 = mm1; v0 = v1;
        }
        FMAG(v0, mm0.y);                             // last group
    }
#undef FMAU
#undef FMAG

    // reduce feats across the 8 groups (same l8), aw across whole wave
#pragma unroll
    for (int b = 0; b < 4; ++b)
#pragma unroll
        for (int cc = 0; cc < 4; ++cc) {
            float v = acc[b][cc];
            v += __shfl_xor(v, 8);
            v += __shfl_xor(v, 16);
            v += __shfl_xor(v, 32);
            acc[b][cc] = v;
        }
    aw += __shfl_xor(aw, 1);
    aw += __shfl_xor(aw, 2);
    aw += __shfl_xor(aw, 4);
    aw += __shfl_xor(aw, 8);
    aw += __shfl_xor(aw, 16);
    aw += __shfl_xor(aw, 32);

    if (g8 == 0) {                                   // lanes 0..7 store
        float* o = out + (size_t)node * 128 + l8 * 4;
#pragma unroll
        for (int b = 0; b < 4; ++b) {
            float4 ov;
            ov.x = fmaf(-128.f, aw, acc[b][0]);
            ov.y = fmaf(-128.f, aw, acc[b][1]);
            ov.z = fmaf(-128.f, aw, acc[b][2]);
            ov.w = fmaf(-128.f, aw, acc[b][3]);
            *(float4*)(o + b * 32) = ov;
        }
    }
}

extern "C" void kernel_launch(void* const* d_in, const int* in_sizes, int n_in,
                              void* d_out, int out_size, void* d_ws, size_t ws_size,
                              hipStream_t stream) {
    const float* x        = (const float*)d_in[0];
    const float* filters  = (const float*)d_in[1];
    const int*   edge_src = (const int*)d_in[2];
    const int*   edge_dst = (const int*)d_in[3];
    const float* edge_w   = (const float*)d_in[4];
    float* out = (float*)d_out;

    char* ws = (char*)d_ws;
    unsigned int*   xi8 = (unsigned int*)  (ws);                          // 12.8 MB
    float*          xsc = (float*)         (ws + 13ll * 1024 * 1024);     // 400 KB
    unsigned short* fB  = (unsigned short*)(ws + 14ll * 1024 * 1024);     // 32 KB
    int*            rp  = (int*)           (ws + 15ll * 1024 * 1024);     // 400 KB

    hipLaunchKernelGGL(k_prep, dim3(12564), dim3(256), 0, stream,
                       filters, fB, edge_dst, rp);
    hipLaunchKernelGGL(k_xf, dim3(1563), dim3(256), 0, stream,
                       x, fB, xi8, xsc);
    hipLaunchKernelGGL(k_aggregate, dim3(25000), dim3(256), 0, stream,
                       xi8, xsc, edge_src, edge_w, rp, out);
}